// Round 7
// baseline (419.434 us; speedup 1.0000x reference)
//
#include <hip/hip_runtime.h>
#include <hip/hip_fp16.h>
#include <math.h>

// ---------------------------------------------------------------------------
// GAT encoder, 2 layers.
//   GEMMs: 2-term split-bf16 MFMA (A_rne*B_hi + A_rne*B_lo). All inputs
//          pre-converted ONCE (x -> bf16, W -> transposed bf16 hi/lo), so the
//          GEMM stages pure bf16 (no conversion VALU in the hot loop).
//          Epilogue writes h fp16 + per-head a_s (fp16) / a_d (fp32).
//   Aggregation: CSR-by-dst; edge-record stream {src, a_s[src] fp16x4}
//   (nontemporal), one random fp16 h-row gather per edge; 2 nodes/wave,
//   depth-3 rotation-free pipeline; nontemporal output stores.
//   NOTE: nontemporal builtins need native ext_vector types, not HIP classes.
// ---------------------------------------------------------------------------

#define LEAKY_SLOPE 0.2f

typedef __attribute__((ext_vector_type(8))) short short8v;   // 8 bf16
typedef __attribute__((ext_vector_type(4))) short short4n;
typedef __attribute__((ext_vector_type(4))) float float4v;
typedef __attribute__((ext_vector_type(4))) unsigned int uint4v;

__device__ __forceinline__ short bf16_rne(float f) {
    unsigned u = __float_as_uint(f);
    return (short)((u + 0x7FFFu + ((u >> 16) & 1u)) >> 16);
}

__device__ __forceinline__ void split_bf16(float f, short& hi, short& lo) {
    unsigned u = __float_as_uint(f);
    hi = (short)(u >> 16);
    float fhi = __uint_as_float(u & 0xFFFF0000u);
    float flo = f - fhi;  // exact
    lo = (short)(__float_as_uint(flo) >> 16);
}

// ---------------- one-time conversions ----------------

__global__ void conv_x(const float* __restrict__ x, short* __restrict__ xb,
                       int n4) {
    int i = blockIdx.x * blockDim.x + threadIdx.x;
    if (i >= n4) return;
    float4 v = ((const float4*)x)[i];
    short4 s;
    s.x = bf16_rne(v.x); s.y = bf16_rne(v.y);
    s.z = bf16_rne(v.z); s.w = bf16_rne(v.w);
    ((short4*)xb)[i] = s;
}

// W [K][256] fp32 -> Wt_hi/Wt_lo [256][K] bf16 (transposed, split)
__global__ __launch_bounds__(256) void conv_W(const float* __restrict__ W,
                                              short* __restrict__ Wt_hi,
                                              short* __restrict__ Wt_lo, int K) {
    __shared__ float tile[32][33];
    int tx = threadIdx.x & 31, ty = threadIdx.x >> 5;   // 32 x 8
    int bx = blockIdx.x, by = blockIdx.y;
#pragma unroll
    for (int i = 0; i < 4; i++) {
        int k = by * 32 + ty + i * 8;
        tile[ty + i * 8][tx] = W[(size_t)k * 256 + bx * 32 + tx];
    }
    __syncthreads();
#pragma unroll
    for (int i = 0; i < 4; i++) {
        int n = bx * 32 + ty + i * 8;
        float f = tile[tx][ty + i * 8];
        short hi, lo;
        split_bf16(f, hi, lo);
        Wt_hi[(size_t)n * K + by * 32 + tx] = hi;
        Wt_lo[(size_t)n * K + by * 32 + tx] = lo;
    }
}

// ---------------- CSR build ----------------

__global__ void hist_kernel(const int* __restrict__ ei, int* __restrict__ cnt,
                            int E, int Etot) {
    int e = blockIdx.x * blockDim.x + threadIdx.x;
    if (e >= Etot) return;
    int dst = (e < E) ? ei[E + e] : (e - E);
    atomicAdd(&cnt[dst], 1);
}

__global__ __launch_bounds__(1024) void scan_block(const int* __restrict__ cnt,
                                                   int* __restrict__ row_start,
                                                   int* __restrict__ partials,
                                                   int n) {
    __shared__ int wsum[16];
    int tid = threadIdx.x, lane = tid & 63, wid = tid >> 6;
    int gi = blockIdx.x * 1024 + tid;
    int v = (gi < n) ? cnt[gi] : 0;
    int x = v;
#pragma unroll
    for (int off = 1; off < 64; off <<= 1) {
        int y = __shfl_up(x, off, 64);
        if (lane >= off) x += y;
    }
    if (lane == 63) wsum[wid] = x;
    __syncthreads();
    if (wid == 0 && lane < 16) {
        int w = wsum[lane];
#pragma unroll
        for (int off = 1; off < 16; off <<= 1) {
            int y = __shfl_up(w, off, 16);
            if (lane >= off) w += y;
        }
        wsum[lane] = w;
    }
    __syncthreads();
    int excl = x - v + ((wid > 0) ? wsum[wid - 1] : 0);
    if (gi < n) row_start[gi] = excl;
    if (tid == 1023) partials[blockIdx.x] = wsum[15];
}

__global__ void scan_partials(int* __restrict__ partials, int nb) {
    int lane = threadIdx.x;  // 64 threads, nb <= 64
    int v = (lane < nb) ? partials[lane] : 0;
    int x = v;
#pragma unroll
    for (int off = 1; off < 64; off <<= 1) {
        int y = __shfl_up(x, off, 64);
        if (lane >= off) x += y;
    }
    if (lane < nb) partials[lane] = x - v;
    if (lane == nb - 1) partials[nb] = x;
}

__global__ __launch_bounds__(1024) void scan_add(int* __restrict__ row_start,
                                                 const int* __restrict__ partials,
                                                 int n, int nb) {
    int gi = blockIdx.x * 1024 + threadIdx.x;
    if (gi < n) row_start[gi] += partials[blockIdx.x];
    if (gi == 0) row_start[n] = partials[nb];
}

__global__ void scatter_kernel(const int* __restrict__ ei,
                               const int* __restrict__ row_start,
                               int* __restrict__ fill,
                               int* __restrict__ edge_src, int E, int Etot) {
    int e = blockIdx.x * blockDim.x + threadIdx.x;
    if (e >= Etot) return;
    int src, dst;
    if (e < E) { src = ei[e]; dst = ei[E + e]; }
    else       { src = e - E; dst = e - E; }
    int pos = row_start[dst] + atomicAdd(&fill[dst], 1);
    edge_src[pos] = src;
}

// per-layer: rec[i] = {src, a_s[src] as 4 x fp16, pad}
__global__ void fill_rec(const int* __restrict__ edge_src,
                         const __half* __restrict__ a_s_h,
                         uint4v* __restrict__ rec, int Etot) {
    int i = blockIdx.x * blockDim.x + threadIdx.x;
    if (i >= Etot) return;
    int s = edge_src[i];
    uint2 as8 = *(const uint2*)&a_s_h[(size_t)s * 4];
    uint4v r = {(unsigned)s, as8.x, as8.y, 0u};
    __builtin_nontemporal_store(r, &rec[i]);
}

// ---------------- all-bf16 MFMA GEMM + fused attention dots ---------------
// C[M,256] = A[M,K] @ (B_hi + B_lo)[K,256]; A bf16 [M][K], B pre-transposed
// bf16 [256][K]. 128x128 tile, BK=32, 2x2 waves of 64x64. C stored fp16.

template <int K>
__global__ __launch_bounds__(256) void gemm_mfma(
    const short* __restrict__ A, const short* __restrict__ Bth,
    const short* __restrict__ Btl, __half* __restrict__ Ch,
    const float* __restrict__ att_src, const float* __restrict__ att_dst,
    __half* __restrict__ a_s_out, float* __restrict__ a_d_out, int M) {
    __shared__ short As[128][40];   // [m][k], pad 32->40
    __shared__ short Bh[128][40];   // [n][k]
    __shared__ short Bl[128][40];

    const int col0 = (blockIdx.x & 1) * 128;
    const int row0 = (blockIdx.x >> 1) * 128;
    const int tid = threadIdx.x;
    const int lane = tid & 63;
    const int wave = tid >> 6;
    const int wr = wave >> 1, wc = wave & 1;
    const int quad = lane >> 4, lc = lane & 15;

    float4v acc[4][4] = {};

    for (int k0 = 0; k0 < K; k0 += 32) {
        // stage A: 128x32 bf16, 16B chunks
#pragma unroll
        for (int i = 0; i < 2; i++) {
            int slot = tid + i * 256;
            int r = slot >> 2;
            int c8 = (slot & 3) * 8;
            short8v v = {};
            int gr = row0 + r;
            if (gr < M) v = *(const short8v*)&A[(size_t)gr * K + k0 + c8];
            *(short8v*)&As[r][c8] = v;
        }
        // stage B hi/lo: coalesced along k from pre-transposed layout
#pragma unroll
        for (int i = 0; i < 2; i++) {
            int slot = tid + i * 256;
            int n = slot >> 2;
            int c8 = (slot & 3) * 8;
            *(short8v*)&Bh[n][c8] =
                *(const short8v*)&Bth[(size_t)(col0 + n) * K + k0 + c8];
            *(short8v*)&Bl[n][c8] =
                *(const short8v*)&Btl[(size_t)(col0 + n) * K + k0 + c8];
        }
        __syncthreads();

        short8v a_f[4], b_hi[4], b_lo[4];
#pragma unroll
        for (int mt = 0; mt < 4; mt++) {
            int r = wr * 64 + mt * 16 + lc;
            a_f[mt] = *(const short8v*)&As[r][quad * 8];
        }
#pragma unroll
        for (int nt = 0; nt < 4; nt++) {
            int n = wc * 64 + nt * 16 + lc;
            b_hi[nt] = *(const short8v*)&Bh[n][quad * 8];
            b_lo[nt] = *(const short8v*)&Bl[n][quad * 8];
        }
#pragma unroll
        for (int mt = 0; mt < 4; mt++)
#pragma unroll
            for (int nt = 0; nt < 4; nt++) {
                acc[mt][nt] = __builtin_amdgcn_mfma_f32_16x16x32_bf16(
                    a_f[mt], b_hi[nt], acc[mt][nt], 0, 0, 0);
                acc[mt][nt] = __builtin_amdgcn_mfma_f32_16x16x32_bf16(
                    a_f[mt], b_lo[nt], acc[mt][nt], 0, 0, 0);
            }
        __syncthreads();
    }

    // ---- epilogue: wave's 64 cols = head; C/D: col=lc(+nt*16), row=quad*4+r
    const int head = (col0 >> 6) + wc;
    float as_c[4], ad_c[4];
#pragma unroll
    for (int nt = 0; nt < 4; nt++) {
        as_c[nt] = att_src[head * 64 + nt * 16 + lc];
        ad_c[nt] = att_dst[head * 64 + nt * 16 + lc];
    }

#pragma unroll
    for (int mt = 0; mt < 4; mt++) {
#pragma unroll
        for (int r = 0; r < 4; r++) {
            int gr = row0 + wr * 64 + mt * 16 + quad * 4 + r;
            float ps = 0.f, pd = 0.f;
#pragma unroll
            for (int nt = 0; nt < 4; nt++) {
                float c = acc[mt][nt][r];
                ps = fmaf(c, as_c[nt], ps);
                pd = fmaf(c, ad_c[nt], pd);
                if (gr < M)
                    Ch[(size_t)gr * 256 + col0 + wc * 64 + nt * 16 + lc] =
                        __float2half(c);
            }
#pragma unroll
            for (int off = 1; off < 16; off <<= 1) {
                ps += __shfl_xor(ps, off, 64);
                pd += __shfl_xor(pd, off, 64);
            }
            if (lc == 0 && gr < M) {
                a_s_out[gr * 4 + head] = __float2half(ps);
                a_d_out[gr * 4 + head] = pd;
            }
        }
    }
}

// ---------------- fused softmax + aggregate + bias + elu ----------------
// 2 nodes/wave (32 lanes/node, 16B/lane gathers). Depth-3 pipeline, no movs.

template <bool OUT_BF16>
__global__ __launch_bounds__(256) void gat_aggregate(
    const __half* __restrict__ hh, const uint4v* __restrict__ rec,
    const float* __restrict__ a_d, const int* __restrict__ row_start,
    const float* __restrict__ bias, void* __restrict__ outp, int n) {
    int wid = (blockIdx.x * blockDim.x + threadIdx.x) >> 6;
    int lane = threadIdx.x & 63;
    int half = lane >> 5, l32 = lane & 31;
    int node = wid * 2 + half;
    bool valid = (node < n);
    int nd = valid ? node : 0;
    int head = l32 >> 3;

    float ad = a_d[nd * 4 + head];
    int beg = row_start[nd];
    int end = valid ? row_start[nd + 1] : beg;

    float l = 0.f;
    float acc[8] = {};

    int em1 = (end > beg) ? (end - 1) : beg;
    uint4v r0 = __builtin_nontemporal_load(&rec[beg]);
    uint4v r1 = __builtin_nontemporal_load(&rec[min(beg + 1, em1)]);
    uint4v r2 = __builtin_nontemporal_load(&rec[min(beg + 2, em1)]);

#define GATH(rr) (*(const uint4v*)&hh[(size_t)(rr).x * 256 + l32 * 8])
#define PROC(rr, vv)                                                      \
    {                                                                     \
        unsigned u = (head & 2) ? (rr).z : (rr).y;                        \
        unsigned short us = (head & 1) ? (unsigned short)(u >> 16)        \
                                       : (unsigned short)(u & 0xFFFFu);   \
        float as = __half2float(*(const __half*)&us);                     \
        float e = as + ad;                                                \
        e = (e > 0.f) ? e : LEAKY_SLOPE * e;                              \
        float w = __expf(e);                                              \
        l += w;                                                           \
        const __half2* hp = (const __half2*)&(vv);                        \
        _Pragma("unroll") for (int j = 0; j < 4; j++) {                   \
            float2 f = __half22float2(hp[j]);                             \
            acc[2 * j] = fmaf(w, f.x, acc[2 * j]);                        \
            acc[2 * j + 1] = fmaf(w, f.y, acc[2 * j + 1]);                \
        }                                                                 \
    }

    uint4v h0 = GATH(r0);
    uint4v h1 = GATH(r1);
    uint4v h2;

    int s = beg;
    while (s < end) {
        h2 = GATH(r2);
        PROC(r0, h0);
        r0 = __builtin_nontemporal_load(&rec[min(s + 3, em1)]);
        if (++s >= end) break;
        h0 = GATH(r0);
        PROC(r1, h1);
        r1 = __builtin_nontemporal_load(&rec[min(s + 3, em1)]);
        if (++s >= end) break;
        h1 = GATH(r1);
        PROC(r2, h2);
        r2 = __builtin_nontemporal_load(&rec[min(s + 3, em1)]);
        ++s;
    }
#undef GATH
#undef PROC

    if (valid) {
        float r = 1.f / l;
        float4 b0 = *(const float4*)&bias[l32 * 8];
        float4 b1 = *(const float4*)&bias[l32 * 8 + 4];
        float o[8];
        o[0] = fmaf(acc[0], r, b0.x); o[1] = fmaf(acc[1], r, b0.y);
        o[2] = fmaf(acc[2], r, b0.z); o[3] = fmaf(acc[3], r, b0.w);
        o[4] = fmaf(acc[4], r, b1.x); o[5] = fmaf(acc[5], r, b1.y);
        o[6] = fmaf(acc[6], r, b1.z); o[7] = fmaf(acc[7], r, b1.w);
#pragma unroll
        for (int j = 0; j < 8; j++)
            o[j] = (o[j] > 0.f) ? o[j] : __expf(o[j]) - 1.f;
        if constexpr (OUT_BF16) {
            short4n ob0, ob1;
            ob0.x = bf16_rne(o[0]); ob0.y = bf16_rne(o[1]);
            ob0.z = bf16_rne(o[2]); ob0.w = bf16_rne(o[3]);
            ob1.x = bf16_rne(o[4]); ob1.y = bf16_rne(o[5]);
            ob1.z = bf16_rne(o[6]); ob1.w = bf16_rne(o[7]);
            short* outb = (short*)outp;
            __builtin_nontemporal_store(ob0,
                (short4n*)&outb[(size_t)node * 256 + l32 * 8]);
            __builtin_nontemporal_store(ob1,
                (short4n*)&outb[(size_t)node * 256 + l32 * 8 + 4]);
        } else {
            float4v of0 = {o[0], o[1], o[2], o[3]};
            float4v of1 = {o[4], o[5], o[6], o[7]};
            float* outf = (float*)outp;
            __builtin_nontemporal_store(of0,
                (float4v*)&outf[(size_t)node * 256 + l32 * 8]);
            __builtin_nontemporal_store(of1,
                (float4v*)&outf[(size_t)node * 256 + l32 * 8 + 4]);
        }
    }
}

// ---------------- launch ----------------

extern "C" void kernel_launch(void* const* d_in, const int* in_sizes, int n_in,
                              void* d_out, int out_size, void* d_ws, size_t ws_size,
                              hipStream_t stream) {
    const float* x   = (const float*)d_in[0];
    const int*   ei  = (const int*)d_in[1];
    const float* W1  = (const float*)d_in[2];
    const float* as1 = (const float*)d_in[3];
    const float* ad1 = (const float*)d_in[4];
    const float* b1  = (const float*)d_in[5];
    const float* W2  = (const float*)d_in[6];
    const float* as2 = (const float*)d_in[7];
    const float* ad2 = (const float*)d_in[8];
    const float* b2  = (const float*)d_in[9];
    float* out = (float*)d_out;

    const int N = in_sizes[0] / 128;
    const int E = in_sizes[1] / 2;
    const int Etot = E + N;
    const int NB = (N + 1023) / 1024;   // scan blocks (<= 64)

    // workspace layout (16B-aligned large segments first)
    __half* h_half = (__half*)d_ws;                        // N*256 fp16
    short*  x1_bf  = (short*)(h_half + (size_t)N * 256);   // N*256 bf16
    uint4v* rec    = (uint4v*)(x1_bf + (size_t)N * 256);   // Etot x 16B
    short*  x_bf   = (short*)(rec + Etot);                 // N*128 bf16
    short*  W1t_hi = x_bf + (size_t)N * 128;               // 256*128
    short*  W1t_lo = W1t_hi + 256 * 128;                   // 256*128
    short*  W2t_hi = W1t_lo + 256 * 128;                   // 256*256
    short*  W2t_lo = W2t_hi + 256 * 256;                   // 256*256
    __half* a_s_h  = (__half*)(W2t_lo + 256 * 256);        // N*4 fp16
    float*  a_d    = (float*)(a_s_h + (size_t)N * 4);      // N*4 fp32
    int*    cnt    = (int*)(a_d + (size_t)N * 4);          // N
    int*    fill   = cnt + N;                              // N
    int*    row_st = fill + N;                             // N+1
    int*    edge_src = row_st + (N + 1);                   // Etot
    int*    partials = edge_src + Etot;                    // NB+1

    // one-time conversions (independent of CSR chain)
    conv_x<<<(N * 128 / 4 + 255) / 256, 256, 0, stream>>>(x, x_bf, N * 128 / 4);
    conv_W<<<dim3(8, 128 / 32), 256, 0, stream>>>(W1, W1t_hi, W1t_lo, 128);
    conv_W<<<dim3(8, 256 / 32), 256, 0, stream>>>(W2, W2t_hi, W2t_lo, 256);

    // CSR build
    hipMemsetAsync(cnt, 0, sizeof(int) * 2 * (size_t)N, stream);  // cnt + fill
    int eblocks = (Etot + 255) / 256;
    hist_kernel<<<eblocks, 256, 0, stream>>>(ei, cnt, E, Etot);
    scan_block<<<NB, 1024, 0, stream>>>(cnt, row_st, partials, N);
    scan_partials<<<1, 64, 0, stream>>>(partials, NB);
    scan_add<<<NB, 1024, 0, stream>>>(row_st, partials, N, NB);
    scatter_kernel<<<eblocks, 256, 0, stream>>>(ei, row_st, fill, edge_src, E, Etot);

    dim3 ggrid(2 * ((N + 127) / 128));
    int ablocks = (N + 7) / 8;   // 8 nodes per 256-thread block

    // layer 1
    gemm_mfma<128><<<ggrid, 256, 0, stream>>>(x_bf, W1t_hi, W1t_lo, h_half,
                                              as1, ad1, a_s_h, a_d, N);
    fill_rec<<<eblocks, 256, 0, stream>>>(edge_src, a_s_h, rec, Etot);
    gat_aggregate<true><<<ablocks, 256, 0, stream>>>(h_half, rec, a_d, row_st,
                                                     b1, x1_bf, N);
    // layer 2
    gemm_mfma<256><<<ggrid, 256, 0, stream>>>(x1_bf, W2t_hi, W2t_lo, h_half,
                                              as2, ad2, a_s_h, a_d, N);
    fill_rec<<<eblocks, 256, 0, stream>>>(edge_src, a_s_h, rec, Etot);
    gat_aggregate<false><<<ablocks, 256, 0, stream>>>(h_half, rec, a_d, row_st,
                                                      b2, out, N);
}